// Round 6
// baseline (100.312 us; speedup 1.0000x reference)
//
#include <hip/hip_runtime.h>
#include <math.h>

// ---------------------------------------------------------------------------
// QuantumClassifier_v2 on MI355X — ONE kernel, 128 blocks (1 per batch row),
// 256 threads. Entire per-row chain in LDS/registers, no global
// intermediates, no atomics, d_ws unused:
//   h = (x[b]@W_down + b_down)/pi
//   4 Clements interferometers: barrier-free per-thread register column sweep
//   U1 = WR1 diag(e^{ih}) WL1          (diag fused into matmul)
//   e1 = 252 no-bunching |perm5|^2     (one per thread)
//   phi2 fold; UF = WRF diag(e^{i phi2}) WLF
//   out[b] = sum_k |perm5(UF rows_k)|^2/norm_k * W_out[k]  (8 perms/thread)
//            + b_out
// Unranking = register-only binomial walk (exact fp32; values < 2^14).
// Native __sincosf (inputs < 2pi; absmax ~6e-5 << 1.1e-3 threshold).
// ---------------------------------------------------------------------------

#define PI_F 3.14159265358979323846f

__device__ __forceinline__ float2 cmul(float2 a, float2 b) {
  return make_float2(fmaf(a.x, b.x, -a.y * b.y), fmaf(a.x, b.y, a.y * b.x));
}
__device__ __forceinline__ float2 cadd(float2 a, float2 b) {
  return make_float2(a.x + b.x, a.y + b.y);
}
__device__ __forceinline__ float2 cscale(float2 a, float s) {
  return make_float2(a.x * s, a.y * s);
}
__device__ __forceinline__ float2 imul(float2 a) {  // i*a
  return make_float2(-a.y, a.x);
}

// Register-only lexicographic unranking of 5-combinations of {0..N-1}.
// cnt0 = C(N-1,4), m0 = N-1. All intermediates are exact integers in fp32.
__device__ __forceinline__ void unrank5f(int rank, float cnt0, float m0,
                                         int c[5]) {
  float r = (float)rank;
  float cnt = cnt0, m = m0, j = 4.f;
  int x = 0;
#pragma unroll
  for (int i = 0; i < 5; i++) {
    while (r >= cnt) {            // skip value x
      r -= cnt;
      cnt = cnt * (m - j) / m;    // C(m-1, j)
      m -= 1.f;
      x++;
    }
    c[i] = x;                     // take value x
    cnt = cnt * j / m;            // C(m-1, j-1)
    m -= 1.f;
    j -= 1.f;
    x++;
  }
}

__device__ __forceinline__ float2 prod5(const float2 rs[5]) {
  return cmul(cmul(cmul(rs[0], rs[1]), cmul(rs[2], rs[3])), rs[4]);
}

// Glynn permanent of 5x5 complex, Gray-code, fully unrolled (result = sum/16).
__device__ __forceinline__ float2 perm5(const float2 M[5][5]) {
  float2 rs[5];
#pragma unroll
  for (int j = 0; j < 5; j++) {
    rs[j] = M[0][j];
#pragma unroll
    for (int i = 1; i < 5; i++) rs[j] = cadd(rs[j], M[i][j]);
  }
  float2 acc = prod5(rs);
#pragma unroll
  for (int t = 1; t < 16; t++) {
    const int g = t ^ (t >> 1);
    const int bit = (t & 1) ? 0 : ((t & 2) ? 1 : ((t & 4) ? 2 : 3));  // ctz
    const int i = bit + 1;
    const float step = ((g >> bit) & 1) ? -2.0f : 2.0f;
#pragma unroll
    for (int j = 0; j < 5; j++) {
      rs[j].x = fmaf(step, M[i][j].x, rs[j].x);
      rs[j].y = fmaf(step, M[i][j].y, rs[j].y);
    }
    float2 p = prod5(rs);
    const float s = (__popc(g) & 1) ? -1.0f : 1.0f;
    acc.x = fmaf(s, p.x, acc.x);
    acc.y = fmaf(s, p.y, acc.y);
  }
  return make_float2(acc.x * (1.0f / 16.0f), acc.y * (1.0f / 16.0f));
}

__global__ __launch_bounds__(256) void k_all(
    const float* __restrict__ x, const float* __restrict__ Wd,
    const float* __restrict__ bd, const float* __restrict__ ph_l1,
    const float* __restrict__ ph_r1, const float* __restrict__ ph_lf,
    const float* __restrict__ ph_rf, const float* __restrict__ Wout,
    const float* __restrict__ bout, float* __restrict__ out) {
  const int b = blockIdx.x, tid = threadIdx.x;

  __shared__ float2 T[4][45][4];   // MZI 2x2 blocks
  __shared__ float2 Ui[4][100];    // 0=WL1, 1=WR1, 2=WLF, 3=WRF
  __shared__ float2 Ub[100];       // U1, then UF
  __shared__ float  e1s[252];
  __shared__ float  red[4][10];
  __shared__ float2 v[10];

  // ---- head GEMV accumulation (registers) ----
  float hacc[10];
#pragma unroll
  for (int c = 0; c < 10; c++) hacc[c] = 0.f;
  for (int i = tid; i < 784; i += 256) {
    float xv = x[b * 784 + i];
    const float* w = Wd + i * 10;
#pragma unroll
    for (int c = 0; c < 10; c++) hacc[c] = fmaf(xv, w[c], hacc[c]);
  }

  // ---- MZI T-blocks for all 4 interferometers (native sincos) ----
  if (tid < 180) {
    const int which = tid / 45, m = tid % 45;
    const float* ph = (which == 0) ? ph_l1
                    : (which == 1) ? ph_r1
                    : (which == 2) ? ph_lf : ph_rf;
    float t1 = ph[m * 2 + 0], t2 = ph[m * 2 + 1];
    float s1, c1, s2, c2;
    __sincosf(t1, &s1, &c1);
    __sincosf(t2, &s2, &c2);
    float2 e2  = make_float2(c2, s2);
    float2 e1m = make_float2(c1 - 1.f, s1);
    float2 e1p = make_float2(c1 + 1.f, s1);
    T[which][m][0] = cscale(cmul(e2, e1m), 0.5f);
    T[which][m][1] = cscale(cmul(e2, imul(e1p)), 0.5f);
    T[which][m][2] = cscale(imul(e1p), 0.5f);
    T[which][m][3] = make_float2(0.5f * (1.f - c1), -0.5f * s1);
  }

  // ---- head reduction into LDS ----
  {
    const int lane = tid & 63, wave = tid >> 6;
#pragma unroll
    for (int c = 0; c < 10; c++) {
      float r = hacc[c];
#pragma unroll
      for (int d = 32; d > 0; d >>= 1) r += __shfl_down(r, d);
      if (lane == 0) red[wave][c] = r;
    }
  }
  __syncthreads();  // (1) T, red ready

  // ---- barrier-free column sweep: thread owns column n of interferometer
  //      `which`; both loops unrolled -> static register indexing. ----
  if (tid < 40) {
    const int which = tid / 10, n = tid % 10;
    float2 u[10];
#pragma unroll
    for (int m = 0; m < 10; m++)
      u[m] = make_float2(m == n ? 1.f : 0.f, 0.f);
    int kb = 0;
#pragma unroll
    for (int layer = 0; layer < 10; layer++) {
      const int start = layer & 1;
      const int npairs = 5 - start;
#pragma unroll
      for (int pi = 0; pi < 5; pi++) {
        if (pi < npairs) {
          const int p = start + 2 * pi;
          const int k = kb + pi;
          float2 u0 = u[p], u1 = u[p + 1];
          u[p]     = cadd(cmul(T[which][k][0], u0), cmul(T[which][k][1], u1));
          u[p + 1] = cadd(cmul(T[which][k][2], u0), cmul(T[which][k][3], u1));
        }
      }
      kb += npairs;
    }
#pragma unroll
    for (int m = 0; m < 10; m++) Ui[which][m * 10 + n] = u[m];
  } else if (tid >= 64 && tid < 74) {
    // wave 1 computes v = e^{i h} concurrently with the sweep
    const int c = tid - 64;
    float s = red[0][c] + red[1][c] + red[2][c] + red[3][c] + bd[c];
    s *= (1.0f / PI_F);
    float sn, cs;
    __sincosf(s, &sn, &cs);
    v[c] = make_float2(cs, sn);
  }
  __syncthreads();  // (2) Ui, v ready

  // ---- U1 = WR1 diag(v) WL1 (diag fused) ----
  if (tid < 100) {
    const int m = tid / 10, n = tid % 10;
    float2 acc = make_float2(0.f, 0.f);
#pragma unroll
    for (int k = 0; k < 10; k++)
      acc = cadd(acc, cmul(cmul(Ui[1][m * 10 + k], v[k]), Ui[0][k * 10 + n]));
    Ub[tid] = acc;
  }
  __syncthreads();  // (3) U1 ready

  // ---- e1: 252 no-bunching permanents ----
  if (tid < 252) {
    int c[5];
    unrank5f(tid, 126.f, 9.f, c);  // C(9,4)=126
    float2 M[5][5];
#pragma unroll
    for (int i = 0; i < 5; i++)
#pragma unroll
      for (int j = 0; j < 5; j++) M[i][j] = Ub[c[i] * 10 + 2 * j];
    float2 p = perm5(M);
    e1s[tid] = p.x * p.x + p.y * p.y;
  }
  __syncthreads();  // (4) e1 ready

  // ---- phi2 fold + v = e^{i phi2} ----
  if (tid < 10) {
    float s = 0.f;
    for (int idx = tid; idx < 252; idx += 10) s += e1s[idx];
    float sn, cs;
    __sincosf(s, &sn, &cs);
    v[tid] = make_float2(cs, sn);
  }
  __syncthreads();  // (5) v ready

  // ---- UF = WRF diag(v) WLF ----
  if (tid < 100) {
    const int m = tid / 10, n = tid % 10;
    float2 acc = make_float2(0.f, 0.f);
#pragma unroll
    for (int k = 0; k < 10; k++)
      acc = cadd(acc, cmul(cmul(Ui[3][m * 10 + k], v[k]), Ui[2][k * 10 + n]));
    Ub[tid] = acc;
  }
  __syncthreads();  // (6) UF ready

  // ---- tail: all 2002 bunched permanents, 8 per thread, fused W_out ----
  float acc[10];
#pragma unroll
  for (int c = 0; c < 10; c++) acc[c] = 0.f;
#pragma unroll
  for (int it = 0; it < 8; it++) {
    const int k = tid + it * 256;
    if (k < 2002) {
      int c5[5];
      unrank5f(k, 715.f, 13.f, c5);  // C(13,4)=715
      int modes[5];
#pragma unroll
      for (int i = 0; i < 5; i++) modes[i] = c5[i] - i;  // non-decreasing
      float2 M[5][5];
#pragma unroll
      for (int i = 0; i < 5; i++)
#pragma unroll
        for (int j = 0; j < 5; j++) M[i][j] = Ub[modes[i] * 10 + 2 * j];
      float2 p = perm5(M);
      // norm = prod of factorials of multiplicities via run-position product
      float norm = 1.f, cnt = 1.f;
#pragma unroll
      for (int i = 1; i < 5; i++) {
        cnt = (modes[i] == modes[i - 1]) ? cnt + 1.f : 1.f;
        norm *= cnt;
      }
      const float pv = (p.x * p.x + p.y * p.y) / norm;
      const float2* w2 = (const float2*)Wout + k * 5;
#pragma unroll
      for (int c = 0; c < 5; c++) {
        float2 w = w2[c];
        acc[2 * c + 0] = fmaf(pv, w.x, acc[2 * c + 0]);
        acc[2 * c + 1] = fmaf(pv, w.y, acc[2 * c + 1]);
      }
    }
  }

  // ---- final block reduction + bias; single writer per row ----
  {
    const int lane = tid & 63, wave = tid >> 6;
#pragma unroll
    for (int c = 0; c < 10; c++) {
      float r = acc[c];
#pragma unroll
      for (int d = 32; d > 0; d >>= 1) r += __shfl_down(r, d);
      if (lane == 0) red[wave][c] = r;
    }
  }
  __syncthreads();
  if (tid < 10) {
    float s = red[0][tid] + red[1][tid] + red[2][tid] + red[3][tid];
    out[b * 10 + tid] = s + bout[tid];
  }
}

extern "C" void kernel_launch(void* const* d_in, const int* in_sizes, int n_in,
                              void* d_out, int out_size, void* d_ws,
                              size_t ws_size, hipStream_t stream) {
  const float* x    = (const float*)d_in[0];  // [128,784]
  const float* Wd   = (const float*)d_in[1];  // [784,10]
  const float* bd   = (const float*)d_in[2];  // [10]
  const float* pl1  = (const float*)d_in[3];  // [45,2]
  const float* pr1  = (const float*)d_in[4];  // [45,2]
  const float* plf  = (const float*)d_in[5];  // [45,2]
  const float* prf  = (const float*)d_in[6];  // [45,2]
  const float* Wout = (const float*)d_in[7];  // [2002,10]
  const float* bout = (const float*)d_in[8];  // [10]
  float* out = (float*)d_out;                 // [128,10]

  k_all<<<128, 256, 0, stream>>>(x, Wd, bd, pl1, pr1, plf, prf, Wout, bout,
                                 out);
}

// Round 7
// 85.867 us; speedup vs baseline: 1.1682x; 1.1682x over previous
//
#include <hip/hip_runtime.h>
#include <math.h>

// ---------------------------------------------------------------------------
// QuantumClassifier_v2 on MI355X, two kernels (R4 structure, prefix
// wave-specialized):
//  k_prefix (128 blocks, 1/row):
//    wave0 lanes 0-39: MZI T-blocks + register column sweep for the 4
//      interferometers, warp-synchronous (DS ops of a wave are in-order —
//      no barrier between T write and read).
//    wave2: whole GEMV h=(x[b]@Wd+bd)/pi with float4 loads, in-wave butterfly
//      reduce, writes v=e^{ih}. Overlaps the interferometer build.
//    then: U1 (diag fused) -> e1 (252 perms) -> phi2 -> UF -> ws. 4 barriers.
//  k_perms (1024 blocks, 8/row): one bunched permanent per thread, fused
//    with W_out; block-reduce + atomicAdd into out (seeded with b_out).
// Unranking = register-only binomial walk (exact fp32; values < 2^14).
// ---------------------------------------------------------------------------

#define PI_F 3.14159265358979323846f

__device__ __forceinline__ float2 cmul(float2 a, float2 b) {
  return make_float2(fmaf(a.x, b.x, -a.y * b.y), fmaf(a.x, b.y, a.y * b.x));
}
__device__ __forceinline__ float2 cadd(float2 a, float2 b) {
  return make_float2(a.x + b.x, a.y + b.y);
}
__device__ __forceinline__ float2 cscale(float2 a, float s) {
  return make_float2(a.x * s, a.y * s);
}
__device__ __forceinline__ float2 imul(float2 a) {  // i*a
  return make_float2(-a.y, a.x);
}

// Register-only lexicographic unranking of 5-combinations of {0..N-1}.
__device__ __forceinline__ void unrank5f(int rank, float cnt0, float m0,
                                         int c[5]) {
  float r = (float)rank;
  float cnt = cnt0, m = m0, j = 4.f;
  int x = 0;
#pragma unroll
  for (int i = 0; i < 5; i++) {
    while (r >= cnt) {            // skip value x
      r -= cnt;
      cnt = cnt * (m - j) / m;    // C(m-1, j)
      m -= 1.f;
      x++;
    }
    c[i] = x;                     // take value x
    cnt = cnt * j / m;            // C(m-1, j-1)
    m -= 1.f;
    j -= 1.f;
    x++;
  }
}

__device__ __forceinline__ float2 prod5(const float2 rs[5]) {
  return cmul(cmul(cmul(rs[0], rs[1]), cmul(rs[2], rs[3])), rs[4]);
}

// Glynn permanent of 5x5 complex, Gray-code, fully unrolled (result = sum/16).
__device__ __forceinline__ float2 perm5(const float2 M[5][5]) {
  float2 rs[5];
#pragma unroll
  for (int j = 0; j < 5; j++) {
    rs[j] = M[0][j];
#pragma unroll
    for (int i = 1; i < 5; i++) rs[j] = cadd(rs[j], M[i][j]);
  }
  float2 acc = prod5(rs);
#pragma unroll
  for (int t = 1; t < 16; t++) {
    const int g = t ^ (t >> 1);
    const int bit = (t & 1) ? 0 : ((t & 2) ? 1 : ((t & 4) ? 2 : 3));  // ctz
    const int i = bit + 1;
    const float step = ((g >> bit) & 1) ? -2.0f : 2.0f;
#pragma unroll
    for (int j = 0; j < 5; j++) {
      rs[j].x = fmaf(step, M[i][j].x, rs[j].x);
      rs[j].y = fmaf(step, M[i][j].y, rs[j].y);
    }
    float2 p = prod5(rs);
    const float s = (__popc(g) & 1) ? -1.0f : 1.0f;
    acc.x = fmaf(s, p.x, acc.x);
    acc.y = fmaf(s, p.y, acc.y);
  }
  return make_float2(acc.x * (1.0f / 16.0f), acc.y * (1.0f / 16.0f));
}

// ---------------------------------------------------------------------------
// Kernel 1: everything through UF; one block per batch row.
// ---------------------------------------------------------------------------
__global__ __launch_bounds__(256) void k_prefix(
    const float* __restrict__ x, const float* __restrict__ Wd,
    const float* __restrict__ bd, const float* __restrict__ ph_l1,
    const float* __restrict__ ph_r1, const float* __restrict__ ph_lf,
    const float* __restrict__ ph_rf, const float* __restrict__ bout,
    float2* __restrict__ UFws, float* __restrict__ out) {
  const int b = blockIdx.x, tid = threadIdx.x;

  __shared__ float2 T[4][45][4];   // MZI 2x2 blocks
  __shared__ float2 Ui[4][100];    // 0=WL1, 1=WR1, 2=WLF, 3=WRF
  __shared__ float2 Ub[100];       // U1, then UF
  __shared__ float  e1s[252];
  __shared__ float2 v[10];

  if (tid < 64) {
    // ---- wave 0, lanes 0-39: T-blocks + register column sweep,
    //      warp-synchronous (same wave writes then reads T) ----
    if (tid < 40) {
      const int which = tid / 10, n = tid % 10;
      const float* ph = (which == 0) ? ph_l1
                      : (which == 1) ? ph_r1
                      : (which == 2) ? ph_lf : ph_rf;
      // lane (which,n) computes T for MZIs m = n, n+10, ..., <45
#pragma unroll
      for (int t5 = 0; t5 < 5; t5++) {
        const int m = n + 10 * t5;
        if (m < 45) {
          float t1 = ph[m * 2 + 0], t2 = ph[m * 2 + 1];
          float s1, c1, s2, c2;
          __sincosf(t1, &s1, &c1);
          __sincosf(t2, &s2, &c2);
          float2 e2  = make_float2(c2, s2);
          float2 e1m = make_float2(c1 - 1.f, s1);
          float2 e1p = make_float2(c1 + 1.f, s1);
          T[which][m][0] = cscale(cmul(e2, e1m), 0.5f);
          T[which][m][1] = cscale(cmul(e2, imul(e1p)), 0.5f);
          T[which][m][2] = cscale(imul(e1p), 0.5f);
          T[which][m][3] = make_float2(0.5f * (1.f - c1), -0.5f * s1);
        }
      }
      // column sweep: this thread owns column n of interferometer `which`
      float2 u[10];
#pragma unroll
      for (int m = 0; m < 10; m++)
        u[m] = make_float2(m == n ? 1.f : 0.f, 0.f);
      int kb = 0;
#pragma unroll
      for (int layer = 0; layer < 10; layer++) {
        const int start = layer & 1;
        const int npairs = 5 - start;
#pragma unroll
        for (int pi = 0; pi < 5; pi++) {
          if (pi < npairs) {
            const int p = start + 2 * pi;
            const int k = kb + pi;
            float2 u0 = u[p], u1 = u[p + 1];
            u[p]     = cadd(cmul(T[which][k][0], u0), cmul(T[which][k][1], u1));
            u[p + 1] = cadd(cmul(T[which][k][2], u0), cmul(T[which][k][3], u1));
          }
        }
        kb += npairs;
      }
#pragma unroll
      for (int m = 0; m < 10; m++) Ui[which][m * 10 + n] = u[m];
    }
  } else if (tid >= 128 && tid < 192) {
    // ---- wave 2: whole GEMV + in-wave reduce + v = e^{ih} ----
    const int lane = tid - 128;
    float acc[10];
#pragma unroll
    for (int c = 0; c < 10; c++) acc[c] = 0.f;
    const float4* x4 = (const float4*)(x + b * 784);  // 196 float4, 16B-aligned
#pragma unroll
    for (int it = 0; it < 4; it++) {
      const int q = lane + it * 64;
      if (q < 196) {
        float4 xv = x4[q];
        const float4* w4 = (const float4*)(Wd + 40 * q);  // 160B-aligned
        float W[40];
#pragma unroll
        for (int j = 0; j < 10; j++) {
          float4 wv = w4[j];
          W[4 * j + 0] = wv.x; W[4 * j + 1] = wv.y;
          W[4 * j + 2] = wv.z; W[4 * j + 3] = wv.w;
        }
        const float xe[4] = {xv.x, xv.y, xv.z, xv.w};
#pragma unroll
        for (int s = 0; s < 40; s++)
          acc[s % 10] = fmaf(xe[s / 10], W[s], acc[s % 10]);
      }
    }
    // 64-lane butterfly: every lane ends with all 10 totals
#pragma unroll
    for (int d = 32; d > 0; d >>= 1)
#pragma unroll
      for (int c = 0; c < 10; c++) acc[c] += __shfl_xor(acc[c], d);
    if (lane < 10) {
      float s = (acc[lane] + bd[lane]) * (1.0f / PI_F);
      float sn, cs;
      __sincosf(s, &sn, &cs);
      v[lane] = make_float2(cs, sn);
    }
  }
  __syncthreads();  // (1) Ui, v ready

  // ---- U1 = WR1 diag(v) WL1 (diag fused) ----
  if (tid < 100) {
    const int m = tid / 10, n = tid % 10;
    float2 acc = make_float2(0.f, 0.f);
#pragma unroll
    for (int k = 0; k < 10; k++)
      acc = cadd(acc, cmul(cmul(Ui[1][m * 10 + k], v[k]), Ui[0][k * 10 + n]));
    Ub[tid] = acc;
  }
  __syncthreads();  // (2) U1 ready

  // ---- e1: 252 no-bunching permanents ----
  if (tid < 252) {
    int c[5];
    unrank5f(tid, 126.f, 9.f, c);  // C(9,4)=126
    float2 M[5][5];
#pragma unroll
    for (int i = 0; i < 5; i++)
#pragma unroll
      for (int j = 0; j < 5; j++) M[i][j] = Ub[c[i] * 10 + 2 * j];
    float2 p = perm5(M);
    e1s[tid] = p.x * p.x + p.y * p.y;
  }
  __syncthreads();  // (3) e1 ready

  // ---- phi2 fold + v = e^{i phi2} ----
  if (tid < 10) {
    float s = 0.f;
    for (int idx = tid; idx < 252; idx += 10) s += e1s[idx];
    float sn, cs;
    __sincosf(s, &sn, &cs);
    v[tid] = make_float2(cs, sn);
  }
  __syncthreads();  // (4) v ready

  // ---- UF = WRF diag(v) WLF -> global ws ----
  if (tid < 100) {
    const int m = tid / 10, n = tid % 10;
    float2 acc = make_float2(0.f, 0.f);
#pragma unroll
    for (int k = 0; k < 10; k++)
      acc = cadd(acc, cmul(cmul(Ui[3][m * 10 + k], v[k]), Ui[2][k * 10 + n]));
    UFws[b * 100 + tid] = acc;
  }
  if (tid < 10) out[b * 10 + tid] = bout[tid];  // seed bias
}

// ---------------------------------------------------------------------------
// Kernel 2: 8 blocks per batch row; one bunched permanent per thread.
// ---------------------------------------------------------------------------
__global__ __launch_bounds__(256) void k_perms(const float2* __restrict__ UFws,
                                               const float* __restrict__ Wout,
                                               float* __restrict__ out) {
  const int b = blockIdx.x >> 3, chunk = blockIdx.x & 7;
  const int tid = threadIdx.x;
  const int k = chunk * 256 + tid;
  __shared__ float2 U[100];
  __shared__ float red[4][10];
  if (tid < 50)  // float4 staging: 2 complex per thread
    ((float4*)U)[tid] = ((const float4*)(UFws + b * 100))[tid];
  __syncthreads();

  float acc[10];
#pragma unroll
  for (int c = 0; c < 10; c++) acc[c] = 0.f;

  if (k < 2002) {
    int c5[5];
    unrank5f(k, 715.f, 13.f, c5);  // C(13,4)=715
    int modes[5];
#pragma unroll
    for (int i = 0; i < 5; i++) modes[i] = c5[i] - i;  // non-decreasing
    float2 M[5][5];
#pragma unroll
    for (int i = 0; i < 5; i++)
#pragma unroll
      for (int j = 0; j < 5; j++) M[i][j] = U[modes[i] * 10 + 2 * j];
    float2 p = perm5(M);
    // norm = prod of factorials of multiplicities via run-position product
    float norm = 1.f, cnt = 1.f;
#pragma unroll
    for (int i = 1; i < 5; i++) {
      cnt = (modes[i] == modes[i - 1]) ? cnt + 1.f : 1.f;
      norm *= cnt;
    }
    const float pv = (p.x * p.x + p.y * p.y) / norm;
    const float2* w2 = (const float2*)Wout + k * 5;
#pragma unroll
    for (int c = 0; c < 5; c++) {
      float2 w = w2[c];
      acc[2 * c + 0] = pv * w.x;
      acc[2 * c + 1] = pv * w.y;
    }
  }

  const int lane = tid & 63, wave = tid >> 6;
#pragma unroll
  for (int c = 0; c < 10; c++) {
    float r = acc[c];
#pragma unroll
    for (int d = 32; d > 0; d >>= 1) r += __shfl_down(r, d);
    if (lane == 0) red[wave][c] = r;
  }
  __syncthreads();
  if (tid < 10) {
    float s = red[0][tid] + red[1][tid] + red[2][tid] + red[3][tid];
    atomicAdd(&out[b * 10 + tid], s);
  }
}

extern "C" void kernel_launch(void* const* d_in, const int* in_sizes, int n_in,
                              void* d_out, int out_size, void* d_ws,
                              size_t ws_size, hipStream_t stream) {
  const float* x    = (const float*)d_in[0];  // [128,784]
  const float* Wd   = (const float*)d_in[1];  // [784,10]
  const float* bd   = (const float*)d_in[2];  // [10]
  const float* pl1  = (const float*)d_in[3];  // [45,2]
  const float* pr1  = (const float*)d_in[4];  // [45,2]
  const float* plf  = (const float*)d_in[5];  // [45,2]
  const float* prf  = (const float*)d_in[6];  // [45,2]
  const float* Wout = (const float*)d_in[7];  // [2002,10]
  const float* bout = (const float*)d_in[8];  // [10]
  float* out = (float*)d_out;                 // [128,10]

  float2* UFws = (float2*)d_ws;  // 128*100 complex64 = 100 KiB

  k_prefix<<<128, 256, 0, stream>>>(x, Wd, bd, pl1, pr1, plf, prf, bout, UFws,
                                    out);
  k_perms<<<1024, 256, 0, stream>>>(UFws, Wout, out);
}